// Round 11
// baseline (233.925 us; speedup 1.0000x reference)
//
#include <hip/hip_runtime.h>
#include <hip/hip_fp16.h>

#define CLIP_HI (1.0f - 1e-6f)

typedef float f4v __attribute__((ext_vector_type(4)));

__device__ __forceinline__ float tri_(float x) {
    return 2.0f * fabsf(x * 0.5f - floorf(x * 0.5f + 0.5f));
}

__device__ __forceinline__ float clamp01(float x) {
    return fminf(fmaxf(x, 0.0f), CLIP_HI);
}

__device__ __forceinline__ float4 nt_load4(const float* p) {
    f4v v = __builtin_nontemporal_load((const f4v*)p);
    return make_float4(v.x, v.y, v.z, v.w);
}
__device__ __forceinline__ void nt_store4(float* p, float4 v) {
    f4v t = {v.x, v.y, v.z, v.w};
    __builtin_nontemporal_store(t, (f4v*)p);
}

// 8-byte half4 payload (single ds_read_b64 per corner).
// (No 16-B struct-pair casts: r6 showed stack-temp lowering -> scratch.)
struct H4 { __half2 xy, zw; };

// clamp01 caps at 1-1e-6 => u = clamp01(x)*(U-1) < U-1 strictly =>
// u1=u0+1, v1=v0+1 always (no min) — verified numerically r6-r10.
struct BW {
    int i00, i10, i01, i11;
    float w00, w10, w01, w11;
};

template <int U, int V>
__device__ __forceinline__ BW bw2d(float uc, float vc) {
    float u = clamp01(uc) * (float)(U - 1);
    float v = clamp01(vc) * (float)(V - 1);
    float u0f = floorf(u), v0f = floorf(v);
    float fu = u - u0f, fv = v - v0f;
    int u0 = (int)u0f, v0 = (int)v0f;
    BW r;
    r.i00 = u0 * V + v0;
    r.i10 = r.i00 + V;
    r.i01 = r.i00 + 1;
    r.i11 = r.i10 + 1;
    float gu = 1.0f - fu, gv = 1.0f - fv;
    r.w00 = gu * gv; r.w10 = fu * gv; r.w01 = gu * fv; r.w11 = fu * fv;
    return r;
}

__device__ __forceinline__ float4 h4_blend(H4 A, H4 B, H4 C, H4 D, const BW& b) {
    float2 Axy = __half22float2(A.xy), Azw = __half22float2(A.zw);
    float2 Bxy = __half22float2(B.xy), Bzw = __half22float2(B.zw);
    float2 Cxy = __half22float2(C.xy), Czw = __half22float2(C.zw);
    float2 Dxy = __half22float2(D.xy), Dzw = __half22float2(D.zw);
    return make_float4(
        Axy.x * b.w00 + Bxy.x * b.w10 + Cxy.x * b.w01 + Dxy.x * b.w11,
        Axy.y * b.w00 + Bxy.y * b.w10 + Cxy.y * b.w01 + Dxy.y * b.w11,
        Azw.x * b.w00 + Bzw.x * b.w10 + Czw.x * b.w01 + Dzw.x * b.w11,
        Azw.y * b.w00 + Bzw.y * b.w10 + Czw.y * b.w01 + Dzw.y * b.w11);
}

// 3-channel bilinear: A/B from LDS half2, C from LDS half.
__device__ __forceinline__ float3 blend3(const __half2* tAB, const __half* tC,
                                         const BW& b) {
    float2 A = __half22float2(tAB[b.i00]);
    float2 B = __half22float2(tAB[b.i10]);
    float2 C = __half22float2(tAB[b.i01]);
    float2 D = __half22float2(tAB[b.i11]);
    float3 r;
    r.x = A.x * b.w00 + B.x * b.w10 + C.x * b.w01 + D.x * b.w11;
    r.y = A.y * b.w00 + B.y * b.w10 + C.y * b.w01 + D.y * b.w11;
    r.z = __half2float(tC[b.i00]) * b.w00 + __half2float(tC[b.i10]) * b.w10 +
          __half2float(tC[b.i01]) * b.w01 + __half2float(tC[b.i11]) * b.w11;
    return r;
}

// Prep into d_ws: rsEnc tri'd + split, cg composed, radC half.
//  [0,16K)      rsAB:  __half2[4096]
//  [16K,24K)    rsC:   __half[4096]
//  [24K,32K)    cgComp:__half2[2048]
//  [32K,36.5K)  radC:  __half[2304]
__global__ __launch_bounds__(256) void prep_kernel(const float* __restrict__ t_rs,
                                                   const float* __restrict__ t_cge,
                                                   const float* __restrict__ t_cgd,
                                                   const float* __restrict__ t_rad,
                                                   __half2* __restrict__ o_rsAB,
                                                   __half* __restrict__ o_rsC,
                                                   __half2* __restrict__ o_cg,
                                                   __half* __restrict__ o_radC) {
    int j = blockIdx.x * 256 + threadIdx.x;
    if (j < 64 * 64) {
        float a = tri_(t_rs[j * 3 + 0]);
        float b = tri_(t_rs[j * 3 + 1]);
        float c = tri_(t_rs[j * 3 + 2]);
        o_rsAB[j] = __floats2half2_rn(a, b);
        o_rsC[j]  = __float2half(c);
    }
    if (j < 2048) {
        float cg = tri_(t_cge[j]);
        float u = clamp01(cg) * 95.0f;
        float u0f = floorf(u);
        float fu = u - u0f;
        int u0 = (int)u0f;
        int u1 = min(u0 + 1, 95);
        float2 a = ((const float2*)t_cgd)[u0];
        float2 b = ((const float2*)t_cgd)[u1];
        o_cg[j] = __floats2half2_rn(a.x * (1.0f - fu) + b.x * fu,
                                    a.y * (1.0f - fu) + b.y * fu);
    }
    if (j < 2304) {
        o_radC[j] = __float2half(t_rad[j * 3 + 2]);
    }
}

// RAEnc nearest-neighbor gather (issue early; consume later).
__device__ __forceinline__ float2 gatherRA(const float* __restrict__ tabRAEnc,
                                           float rNx, float aTx) {
    int ui = (int)rintf(clamp01(rNx) * 2047.0f);   // jnp.round = half-to-even
    int vi = (int)rintf(clamp01(aTx) * 2047.0f);
    return ((const float2*)tabRAEnc)[ui * 2048 + vi];
}

// Everything after the RAEnc gather. rsEnc/radAB/LVR/LV/NHL = LDS;
// cg (4 B) + radC (4x 2 B) = divergent reads from small L1-resident
// d_ws tables; gather = global.
template <bool USE_WS>
__device__ __forceinline__ float2 shadeB(
    float rNx, float rNy, float aTy, float nLVx, float nLVy,
    float mLx, float mLy, float sCx, float sCy, float spx, float spy,
    float shx, float shy, float lCx, float lCy,
    float2 raT,
    const __half2* __restrict__ cgComp,
    const float* __restrict__ tabCgEnc, const float* __restrict__ tabCgDec,
    const __half* __restrict__ gRadC, const float* __restrict__ tabRADec,
    const __half2* sRsAB, const __half* sRsC,
    const __half2* sRadAB,
    const __half* sLVR, const H4* sLV, const H4* sNHL)
{
    // --- rsEnc bilinear (LDS; the r10 win: was 16 divergent L1/thread) ---
    float rs0, rs1, rs2;
    {
        BW b = bw2d<64, 64>(rNx, sCx);
        float3 r = blend3(sRsAB, sRsC, b);
        rs0 = r.x; rs1 = r.y; rs2 = r.z;
    }

    // --- composed cgEnc∘cgDec: one 4-B global read (8 KB, L1-resident) ---
    float2 cgC;
    {
        int ci = (int)rintf(clamp01(sCy) * 2047.0f);
        if constexpr (USE_WS) {
            cgC = __half22float2(cgComp[ci]);
        } else {
            float cg = tri_(tabCgEnc[ci]);
            float u = clamp01(cg) * 95.0f;
            float u0f = floorf(u);
            float fu = u - u0f;
            int u0 = (int)u0f;
            int u1 = min(u0 + 1, 95);
            float2 a = ((const float2*)tabCgDec)[u0];
            float2 b = ((const float2*)tabCgDec)[u1];
            cgC = make_float2(a.x * (1.0f - fu) + b.x * fu,
                              a.y * (1.0f - fu) + b.y * fu);
        }
    }

    // --- nlv, nhl (LDS half4) ---
    float4 nlv, nhl;
    {
        BW b = bw2d<32, 32>(nLVx, nLVy);
        nlv = h4_blend(sLV[b.i00], sLV[b.i10], sLV[b.i01], sLV[b.i11], b);
    }
    {
        BW b = bw2d<32, 32>(mLy, nLVx);
        nhl = h4_blend(sNHL[b.i00], sNHL[b.i10], sNHL[b.i01], sNHL[b.i11], b);
    }

    // --- dependent on RAEnc gather result ---
    float ra0 = tri_(raT.x);
    float ra1 = tri_(raT.y);

    float raC0, raC1, raC2;
    {
        BW b = bw2d<48, 48>(ra0, ra1);
        float2 A = __half22float2(sRadAB[b.i00]);
        float2 B = __half22float2(sRadAB[b.i10]);
        float2 C = __half22float2(sRadAB[b.i01]);
        float2 D = __half22float2(sRadAB[b.i11]);
        raC0 = A.x * b.w00 + B.x * b.w10 + C.x * b.w01 + D.x * b.w11;
        raC1 = A.y * b.w00 + B.y * b.w10 + C.y * b.w01 + D.y * b.w11;
        // C channel: 4x 2-B divergent reads from 4.6 KB L1-resident table
        // (the 3.6-KB LDS shave that buys the 3rd block/CU).
        if constexpr (USE_WS) {
            raC2 = __half2float(gRadC[b.i00]) * b.w00 + __half2float(gRadC[b.i10]) * b.w10 +
                   __half2float(gRadC[b.i01]) * b.w01 + __half2float(gRadC[b.i11]) * b.w11;
        } else {
            raC2 = tabRADec[b.i00 * 3 + 2] * b.w00 + tabRADec[b.i10 * 3 + 2] * b.w10 +
                   tabRADec[b.i01 * 3 + 2] * b.w01 + tabRADec[b.i11 * 3 + 2] * b.w11;
        }
    }

    float vTerm;
    {
        BW b = bw2d<32, 32>(nLVx * nLVy, ra0);
        vTerm = __half2float(sLVR[b.i00]) * b.w00 + __half2float(sLVR[b.i10]) * b.w10 +
                __half2float(sLVR[b.i01]) * b.w01 + __half2float(sLVR[b.i11]) * b.w11;
    }

    // --- epilogue arithmetic ---
    float met = mLx;
    float om  = 1.0f - met;
    float cd  = om * lCx;
    float cm0 = spx * 0.1f * om * spy + met * lCx;
    float cm1 = spx * 0.1f * om * (1.0f - spy);
    float cs0 = shx * om * shy;
    float cs1 = shx * om * (1.0f - shy);
    float cc  = 0.0625f * lCy;

    float noh2 = rNy * rNy;
    float den  = raC0 * aTy * aTy + raC1 * noh2 + raC2;
    float dTerm = 0.25f / (nLVy * den * den);

    float x = rs0 * cd * mLy * nlv.y + rs1 * cd * nlv.z + rs2 * cd * nlv.w
            + cm0 * vTerm * nhl.z * dTerm + cs0 * nhl.x;

    float y = ((1.0f - cm1) * nhl.w + cm1) * vTerm * dTerm
            + cs1 * nhl.x
            + cc * nhl.y * nlv.x / (nLVy * (cgC.x * noh2 + cgC.y));

    return make_float2(x, y);
}

// R11: clean occupancy test. r10 (67.5us best) is LDS-capped at 2 blocks/CU
// (56832 B) with stall-dominated execution (VALU 29%, HBM 37%, ideal
// ~32us vs measured 67.5). Change: move ONLY radC (4.6 KB) to d_ws ->
// LDS 52224 <= 53248 -> 3 blocks/CU = 24 waves max; and 1 PAIR per thread
// (grid 2048 = 8 work-blocks/CU, generations 3/3/2) to avoid the r0
// coarse-grid tail trap. Divergent giveback: only 4x 2-B radC reads/elem.
// MEASURED HISTORY: (512,4) no spill = best. 8-waves/EU bound -> 32-VGPR
// clamp -> scratch (WRITE 92-154MB). NEVER. 16-B struct casts -> scratch.
// NEVER. 65024-B-LDS/no-prep binary -> container death (r8/r9). AVOID.
template <bool USE_WS>
__global__ __launch_bounds__(512, 4) void disney_main(
    const float* __restrict__ roughNoh,
    const float* __restrict__ anisoToh,
    const float* __restrict__ nDotLV,
    const float* __restrict__ metalLoh,
    const float* __restrict__ subCg,
    const float* __restrict__ spst,
    const float* __restrict__ shst,
    const float* __restrict__ lumCs,
    const float* __restrict__ tabRAEnc,   // (2048,2048,2) global gather
    const float* __restrict__ tabCgEnc,   // fallback path
    const float* __restrict__ tabCgDec,   // fallback path
    const float* __restrict__ tabRSEnc,   // raw: LDS fill fallback
    const float* __restrict__ tabRADec,   // (48,48,3): AB -> LDS; C fallback
    const __half2* __restrict__ wsRsAB,   // d_ws: rsEnc A/B, tri'd
    const __half*  __restrict__ wsRsC,    // d_ws: rsEnc C, tri'd
    const __half2* __restrict__ cgComp,   // d_ws: composed cg
    const __half*  __restrict__ gRadC,    // d_ws: radC half[2304]
    const float* __restrict__ tabLVR,     // (32,32,1) -> LDS half, tri'd
    const float* __restrict__ tabLV,      // (32,32,4) -> LDS half4, tri'd
    const float* __restrict__ tabNHL,     // (32,32,4) -> LDS half4, tri'd
    float* __restrict__ out,
    int n)
{
    __shared__ __half2 sRsAB[4096];    // 16384 B
    __shared__ __half  sRsC [4096];    //  8192 B
    __shared__ __half2 sRadAB[2304];   //  9216 B
    __shared__ __half  sLVR[1024];     //  2048 B
    __shared__ H4      sLV [1024];     //  8192 B
    __shared__ H4      sNHL[1024];     //  8192 B   -> total 52224 B (3 blk/CU)

    int tid = threadIdx.x;

#pragma unroll
    for (int k = 0; k < 8; ++k) {
        int j = tid + k * 512;
        if constexpr (USE_WS) {
            sRsAB[j] = wsRsAB[j];      // coalesced copies from d_ws
            sRsC[j]  = wsRsC[j];
        } else {
            float a = tri_(tabRSEnc[j * 3 + 0]);
            float b = tri_(tabRSEnc[j * 3 + 1]);
            float c = tri_(tabRSEnc[j * 3 + 2]);
            sRsAB[j] = __floats2half2_rn(a, b);
            sRsC[j]  = __float2half(c);
        }
    }
    for (int j = tid; j < 2304; j += 512) {
        sRadAB[j] = __floats2half2_rn(tabRADec[j * 3 + 0], tabRADec[j * 3 + 1]);
    }
#pragma unroll
    for (int k = 0; k < 2; ++k) {
        int j = tid + k * 512;
        sLVR[j] = __float2half(tri_(tabLVR[j]));
        float4 v = ((const float4*)tabLV)[j];
        H4 h; h.xy = __floats2half2_rn(tri_(v.x), tri_(v.y));
              h.zw = __floats2half2_rn(tri_(v.z), tri_(v.w));
        sLV[j] = h;
        float4 w = ((const float4*)tabNHL)[j];
        H4 h2; h2.xy = __floats2half2_rn(tri_(w.x), tri_(w.y));
               h2.zw = __floats2half2_rn(tri_(w.z), tri_(w.w));
        sNHL[j] = h2;
    }
    __syncthreads();

    int P = (n + 1) >> 1;        // total pairs
    int p = blockIdx.x * 512 + tid;   // ONE pair per thread
    if (p >= P) return;

    if (2 * p + 1 < n) {
        // ---- full pair: float4 loads (16 B/lane), 2 gathers, 2 shades ----
        float4 rN = nt_load4(roughNoh + 4 * p);
        float4 aT = nt_load4(anisoToh + 4 * p);

        float2 raT0 = gatherRA(tabRAEnc, rN.x, aT.x);
        float2 raT1 = gatherRA(tabRAEnc, rN.z, aT.z);

        float4 nLV = nt_load4(nDotLV   + 4 * p);
        float4 mL  = nt_load4(metalLoh + 4 * p);
        float4 sC  = nt_load4(subCg    + 4 * p);
        float4 sp  = nt_load4(spst     + 4 * p);
        float4 sh  = nt_load4(shst     + 4 * p);
        float4 lC  = nt_load4(lumCs    + 4 * p);

        float2 r0 = shadeB<USE_WS>(rN.x, rN.y, aT.y, nLV.x, nLV.y,
                                   mL.x, mL.y, sC.x, sC.y, sp.x, sp.y,
                                   sh.x, sh.y, lC.x, lC.y, raT0,
                                   cgComp, tabCgEnc, tabCgDec, gRadC, tabRADec,
                                   sRsAB, sRsC, sRadAB, sLVR, sLV, sNHL);
        float2 r1 = shadeB<USE_WS>(rN.z, rN.w, aT.w, nLV.z, nLV.w,
                                   mL.z, mL.w, sC.z, sC.w, sp.z, sp.w,
                                   sh.z, sh.w, lC.z, lC.w, raT1,
                                   cgComp, tabCgEnc, tabCgDec, gRadC, tabRADec,
                                   sRsAB, sRsC, sRadAB, sLVR, sLV, sNHL);
        nt_store4(out + 4 * p, make_float4(r0.x, r0.y, r1.x, r1.y));
    } else {
        // ---- rare tail: per-element scalar path ----
#pragma unroll
        for (int k = 0; k < 2; ++k) {
            int e = 2 * p + k;
            if (e >= n) continue;
            float2 rN  = ((const float2*)roughNoh)[e];
            float2 aT  = ((const float2*)anisoToh)[e];
            float2 nLV = ((const float2*)nDotLV)[e];
            float2 mL  = ((const float2*)metalLoh)[e];
            float2 sC  = ((const float2*)subCg)[e];
            float2 sp  = ((const float2*)spst)[e];
            float2 sh  = ((const float2*)shst)[e];
            float2 lC  = ((const float2*)lumCs)[e];
            float2 raT = gatherRA(tabRAEnc, rN.x, aT.x);
            float2 r = shadeB<USE_WS>(rN.x, rN.y, aT.y, nLV.x, nLV.y,
                                      mL.x, mL.y, sC.x, sC.y, sp.x, sp.y,
                                      sh.x, sh.y, lC.x, lC.y, raT,
                                      cgComp, tabCgEnc, tabCgDec, gRadC, tabRADec,
                                      sRsAB, sRsC, sRadAB, sLVR, sLV, sNHL);
            ((float2*)out)[e] = r;
        }
    }
}

extern "C" void kernel_launch(void* const* d_in, const int* in_sizes, int n_in,
                              void* d_out, int out_size, void* d_ws, size_t ws_size,
                              hipStream_t stream) {
    // 0 roughNoh, 1 anisoToh, 2 nDotLV, 3 tDotLV (UNUSED), 4 metalLoh,
    // 5 subCg, 6 spst, 7 shst, 8 lumCs, 9 tabRAEnc, 10 tabCgEnc, 11 tabRSEnc,
    // 12 tabRADec, 13 tabCgDec, 14 tabLVR, 15 tabLV, 16 tabNHL
    const float* roughNoh = (const float*)d_in[0];
    const float* anisoToh = (const float*)d_in[1];
    const float* nDotLV   = (const float*)d_in[2];
    const float* metalLoh = (const float*)d_in[4];
    const float* subCg    = (const float*)d_in[5];
    const float* spst     = (const float*)d_in[6];
    const float* shst     = (const float*)d_in[7];
    const float* lumCs    = (const float*)d_in[8];
    const float* tabRAEnc = (const float*)d_in[9];
    const float* tabCgEnc = (const float*)d_in[10];
    const float* tabRSEnc = (const float*)d_in[11];
    const float* tabRADec = (const float*)d_in[12];
    const float* tabCgDec = (const float*)d_in[13];
    const float* tabLVR   = (const float*)d_in[14];
    const float* tabLV    = (const float*)d_in[15];
    const float* tabNHL   = (const float*)d_in[16];

    int n = in_sizes[0] / 2;   // (N,2)
    float* out = (float*)d_out;

    const int block = 512;
    int P = (n + 1) / 2;       // pairs; one pair per thread
    int grid = (P + block - 1) / block;

    // d_ws: [0,16K) rsAB; [16K,24K) rsC; [24K,32K) cg; [32K,36.5K) radC
    const size_t OFF_RSC  = 4096 * sizeof(__half2);             // 16384
    const size_t OFF_CG   = OFF_RSC + 4096 * sizeof(__half);    // 24576
    const size_t OFF_RADC = OFF_CG + 2048 * sizeof(__half2);    // 32768
    const size_t WS_NEED  = OFF_RADC + 2304 * sizeof(__half);   // 37376
    bool use_ws = ws_size >= WS_NEED;
    __half2* ws_rsAB = (__half2*)d_ws;
    __half*  ws_rsC  = (__half*)((char*)d_ws + OFF_RSC);
    __half2* ws_cg   = (__half2*)((char*)d_ws + OFF_CG);
    __half*  ws_radC = (__half*)((char*)d_ws + OFF_RADC);

    if (use_ws) {
        prep_kernel<<<(64 * 64 + 255) / 256, 256, 0, stream>>>(
            tabRSEnc, tabCgEnc, tabCgDec, tabRADec,
            ws_rsAB, ws_rsC, ws_cg, ws_radC);
        disney_main<true><<<grid, block, 0, stream>>>(
            roughNoh, anisoToh, nDotLV, metalLoh, subCg, spst, shst, lumCs,
            tabRAEnc, tabCgEnc, tabCgDec, tabRSEnc, tabRADec,
            ws_rsAB, ws_rsC, ws_cg, ws_radC,
            tabLVR, tabLV, tabNHL, out, n);
    } else {
        disney_main<false><<<grid, block, 0, stream>>>(
            roughNoh, anisoToh, nDotLV, metalLoh, subCg, spst, shst, lumCs,
            tabRAEnc, tabCgEnc, tabCgDec, tabRSEnc, tabRADec,
            ws_rsAB, ws_rsC, ws_cg, ws_radC,
            tabLVR, tabLV, tabNHL, out, n);
    }
}